// Round 4
// baseline (169.657 us; speedup 1.0000x reference)
//
#include <hip/hip_runtime.h>

// Problem constants (from reference): B=8, E=512, L=4096, D=256, all fp32.
#define B_N 8
#define E_N 512
#define L_N 4096
#define D_N 256

#define SPLITK 8
#define KC_LEN (L_N / SPLITK)   // 512
#define BK 64
#define KC_ITERS (KC_LEN / BK)  // 8

#define ET 128                  // E tile
#define DT 128                  // D tile
#define NTHREADS 512

#define SLICE_ELEMS (B_N * E_N * D_N)           // 1M floats = 4 MB per split slice

typedef __attribute__((ext_vector_type(8))) short short8;   // 8 bf16 (MFMA A/B frag)
typedef __attribute__((ext_vector_type(4))) float f32x4;    // MFMA acc / global float4
typedef __attribute__((ext_vector_type(2))) unsigned int uint2v; // 2x packed bf16 pair

// Packed fp32x2 -> bf16x2 (RNE) in ONE VALU op. src0 -> low 16 bits.
// Replaces ~5 scalar ops/element of the old bit-math f2bf; VALU was 14% busy
// and on the serial critical path between vmcnt-drain and barrier.
__device__ __forceinline__ unsigned cvt_pk_bf16(float lo, float hi) {
    unsigned r;
    asm("v_cvt_pk_bf16_f32 %0, %1, %2" : "=v"(r) : "v"(lo), "v"(hi));
    return r;
}

// LDS tile: [row][64 k] bf16, 128 B per row, NO pad. 16B-chunk XOR swizzle
// (verified R2: SQ_LDS_BANK_CONFLICT 5.2M -> 0). k multiple of 4 at call sites.
__device__ __forceinline__ int swz(int row, int k) {
    return row * 64 + ((((k >> 3) ^ (row & 7)) << 3) | (k & 7));
}

// ---------------- Stage 1: split-K partial GEMM, NO atomics ----------------
__global__ __launch_bounds__(NTHREADS, 4)   // VGPR cap 128 -> keep 2 blocks/CU
void mp_gemm(const float* __restrict__ doc,   // [B, L, D]
             const float* __restrict__ map,   // [B, E, L]
             float* __restrict__ ws)          // [SPLITK, B, E, D] partials
{
    // double-buffered swizzled tiles: 4 x 16 KiB = 64 KiB -> 2 blocks/CU
    __shared__ unsigned short As[2][ET * 64];   // As[m][k] : map tile, K-contig
    __shared__ unsigned short Bs[2][DT * 64];   // Bs[n][k] : doc tile transposed

    // XCD-chunked swizzle: each XCD owns 8 complete (b,kc) groups whose 8
    // tiles share doc/map panels in that XCD's L2.
    const int p    = (int)blockIdx.x;            // 0..511
    const int w    = ((p & 7) << 6) | (p >> 3);
    const int tile = w & 7;        // et*2 + dt
    const int grp  = w >> 3;       // 0..63
    const int b    = grp & 7;
    const int kc   = grp >> 3;     // 0..7

    const int e0  = (tile >> 1) * ET;   // 4 E tiles
    const int d0  = (tile & 1) * DT;    // 2 D tiles
    const int kc0 = kc * KC_LEN;

    const float* docB = doc + (size_t)b * L_N * D_N;
    const float* mapB = map + (size_t)b * E_N * L_N;
    float* wsB = ws + (size_t)kc * SLICE_ELEMS + (size_t)b * E_N * D_N;

    const int tid  = threadIdx.x;
    const int lane = tid & 63;
    const int wave = tid >> 6;     // 0..7

    // ---- staging assignments ----
    const int aRow0 = tid >> 4;    // 0..31 (rows +32r), 16 lanes x 16B contiguous
    const int aCol4 = tid & 15;
    const int kb = tid & 15;       // k block: varies across lanes (LDS chunk spread)
    const int nb = tid >> 4;       // n block (0..31)

    // Distance-2 pipeline: two independent staging sets. A set is consumed
    // (LDS-write) two iterations after its loads are issued -> ~2 full
    // iterations of flight time instead of barrier+MFMA (~500 cy).
    f32x4 ar0[4], br0[4], ar1[4], br1[4];

    #define LOAD_SET(ARS, BRS, K0)                                                         \
        do {                                                                               \
            _Pragma("unroll")                                                              \
            for (int r = 0; r < 4; ++r)                                                    \
                ARS[r] = *(const f32x4*)(mapB + (size_t)(e0 + aRow0 + r * 32) * L_N +      \
                                         (K0) + aCol4 * 4);                                \
            _Pragma("unroll")                                                              \
            for (int i = 0; i < 4; ++i)                                                    \
                BRS[i] = *(const f32x4*)(docB + (size_t)((K0) + kb * 4 + i) * D_N +        \
                                         d0 + nb * 4);                                     \
        } while (0)

    // ---- compute setup: 8 waves in 2(m) x 4(n) grid; each wave 64x32 output ----
    const int wm = wave >> 2;      // 0..1 : 64-row block
    const int wn = wave & 3;       // 0..3 : 32-col block
    const int fm = lane & 15;
    const int q  = lane >> 4;

    f32x4 acc[4][2] = {};

    LOAD_SET(ar0, br0, kc0);            // prologue: tiles 0 and 1 in flight
    LOAD_SET(ar1, br1, kc0 + BK);

    // One iteration: LDS-write from SET (counted vmcnt drains only the oldest
    // set), reissue SET for IT+2, raw barrier (lgkm only -- globals stay in
    // flight), MFMA on buf[IT&1].
    #define ITER_BODY(ARS, BRS, IT)                                                        \
    {                                                                                      \
        const int bi = (IT) & 1;                                                           \
        _Pragma("unroll")                                                                  \
        for (int r = 0; r < 4; ++r) {                                                      \
            uint2v wv;                                                                     \
            wv[0] = cvt_pk_bf16(ARS[r][0], ARS[r][1]);                                     \
            wv[1] = cvt_pk_bf16(ARS[r][2], ARS[r][3]);                                     \
            *(uint2v*)&As[bi][swz(aRow0 + r * 32, aCol4 * 4)] = wv;                        \
        }                                                                                  \
        _Pragma("unroll")                                                                  \
        for (int j = 0; j < 4; ++j) {                                                      \
            uint2v wv;                                                                     \
            wv[0] = cvt_pk_bf16(BRS[0][j], BRS[1][j]);                                     \
            wv[1] = cvt_pk_bf16(BRS[2][j], BRS[3][j]);                                     \
            *(uint2v*)&Bs[bi][swz(nb * 4 + j, kb * 4)] = wv;                               \
        }                                                                                  \
        if ((IT) + 2 < KC_ITERS)                                                           \
            LOAD_SET(ARS, BRS, kc0 + ((IT) + 2) * BK);                                     \
        __builtin_amdgcn_sched_barrier(0);                                                 \
        asm volatile("s_waitcnt lgkmcnt(0)" ::: "memory");                                 \
        __builtin_amdgcn_s_barrier();                                                      \
        __builtin_amdgcn_sched_barrier(0);                                                 \
        _Pragma("unroll")                                                                  \
        for (int kk = 0; kk < 2; ++kk) {                                                   \
            short8 af[4], bf[2];                                                           \
            _Pragma("unroll")                                                              \
            for (int mi = 0; mi < 4; ++mi) {                                               \
                const int m = wm * 64 + mi * 16 + fm;                                      \
                af[mi] = *(const short8*)&As[bi][swz(m, kk * 32 + q * 8)];                 \
            }                                                                              \
            _Pragma("unroll")                                                              \
            for (int ni = 0; ni < 2; ++ni) {                                               \
                const int n = wn * 32 + ni * 16 + fm;                                      \
                bf[ni] = *(const short8*)&Bs[bi][swz(n, kk * 32 + q * 8)];                 \
            }                                                                              \
            _Pragma("unroll")                                                              \
            for (int mi = 0; mi < 4; ++mi)                                                 \
                _Pragma("unroll")                                                          \
                for (int ni = 0; ni < 2; ++ni)                                             \
                    acc[mi][ni] = __builtin_amdgcn_mfma_f32_16x16x32_bf16(                 \
                        af[mi], bf[ni], acc[mi][ni], 0, 0, 0);                             \
        }                                                                                  \
    }

    for (int it = 0; it < KC_ITERS; it += 2) {
        ITER_BODY(ar0, br0, it);        // even iters: set0 -> buf0
        ITER_BODY(ar1, br1, it + 1);    // odd  iters: set1 -> buf1
    }
    #undef ITER_BODY
    #undef LOAD_SET

    // ---- epilogue: plain stores of the partial tile to this block's private
    // workspace slice. C/D layout: col = lane&15, row = (lane>>4)*4 + i.
    #pragma unroll
    for (int mi = 0; mi < 4; ++mi) {
        const int rLoc = wm * 64 + mi * 16 + q * 4;
        #pragma unroll
        for (int ni = 0; ni < 2; ++ni) {
            const int c = d0 + wn * 32 + ni * 16 + fm;
            #pragma unroll
            for (int i = 0; i < 4; ++i) {
                const int rr = rLoc + i;
                wsB[(size_t)(e0 + rr) * D_N + c] = acc[mi][ni][i];
            }
        }
    }
}

// ---------------- Stage 2: reduce slices + scale by 1/len ----------------
__global__ __launch_bounds__(256)
void mp_reduce(const float* __restrict__ ws,    // [SPLITK, B*E*D]
               const float* __restrict__ lens,  // [B, E]
               float* __restrict__ out)         // [B*E*D]
{
    const int t = (int)blockIdx.x * 256 + (int)threadIdx.x;  // float4 index
    const size_t off = (size_t)t * 4;
    const int be = t >> 6;            // D/4 = 64 float4 per (b,e) row

    f32x4 s = {};
    #pragma unroll
    for (int k = 0; k < SPLITK; ++k) {
        const f32x4 v = *(const f32x4*)(ws + (size_t)k * SLICE_ELEMS + off);
        s += v;
    }
    const float il = 1.0f / lens[be];
    s *= il;
    *(f32x4*)(out + off) = s;
}

extern "C" void kernel_launch(void* const* d_in, const int* in_sizes, int n_in,
                              void* d_out, int out_size, void* d_ws, size_t ws_size,
                              hipStream_t stream) {
    const float* doc  = (const float*)d_in[0];  // doc_state [B,L,D]
    const float* map  = (const float*)d_in[1];  // entity_mapping [B,E,L]
    const float* lens = (const float*)d_in[2];  // entity_lens [B,E]
    float* out = (float*)d_out;                 // [B,E,D] fp32
    float* ws  = (float*)d_ws;                  // needs 32 MB (SPLITK slices)

    // No memset needed: stage 1 fully writes every ws element, stage 2 fully
    // overwrites out.
    dim3 grid1(SPLITK * 8 * B_N);   // 512 blocks: 8 tiles x 8 b x 8 kc
    mp_gemm<<<grid1, NTHREADS, 0, stream>>>(doc, map, ws);

    dim3 grid2(SLICE_ELEMS / 4 / 256);  // 1024 blocks
    mp_reduce<<<grid2, 256, 0, stream>>>(ws, lens, out);
}